// Round 4
// baseline (2695.939 us; speedup 1.0000x reference)
//
#include <hip/hip_runtime.h>

// SlowRNN: out[t] = h_{t+1} = tanh(x_t @ Wxh^T + bh + h_t @ Whh^T), h_0 = 0
// T=512, B=64, IN=H=1024.  fp32 in / fp32 out, threshold 2e-2 -> fp16 MFMA compute.
//
// v3: single-round-trip h exchange. h values travel as (tag<<16 | fp16bits) u32
// words via RELAXED agent-scope (sc1) stores/loads. Consumers poll their own h
// words until tag==t: the poll IS the data load. No producer vmcnt, no flags,
// no separate visibility round-trip. Barriers are raw lgkmcnt(0)+s_barrier
// (LDS-only) so x/out HBM traffic never enters the serial chain.
// Protocol safety: parity double-buffer; tags 1..511 never collide with 0xAA
// poison; poll-success over ALL feats proves every producer wave passed its
// prior-step reads => overwrite is WAR-safe. fp16 h exchange validated in v1.
//
// Steady-state serial chain: fire tagged h -> MALL commit -> consumer poll
// detect -> LDS stage -> barrier -> 32 h-MFMAs -> reduce+tanh -> fire next.
// x-side work (prefetch HBM->reg, reg->LDS, 32 x-MFMAs) all off-chain.
// ws: hglob u32[2][64][1024] @0 (512KB). No memset needed (tag scheme).

typedef _Float16 f16;
typedef _Float16 f16x8 __attribute__((ext_vector_type(8)));
typedef float f32x4 __attribute__((ext_vector_type(4)));
typedef unsigned int u32;
typedef unsigned short u16;

#define T_STEPS 512
#define NB 64
#define NH 1024
#define ROWP 1040  // padded LDS row (f16 elems), 2080B stride

__device__ __forceinline__ f16x8 cvt8(const float4 a, const float4 b) {
    f16x8 v;
    v[0] = (f16)a.x; v[1] = (f16)a.y; v[2] = (f16)a.z; v[3] = (f16)a.w;
    v[4] = (f16)b.x; v[5] = (f16)b.y; v[6] = (f16)b.z; v[7] = (f16)b.w;
    return v;
}

__device__ __forceinline__ float fast_tanh(float x) {
    float e = __expf(2.0f * x);
    return 1.0f - 2.0f / (e + 1.0f);
}

__device__ __forceinline__ void lds_barrier() {
    // LDS-only drain + barrier: vmcnt (x prefetch / out stores) stays in flight.
    asm volatile("s_waitcnt lgkmcnt(0)\ns_barrier" ::: "memory");
}

extern "C" __global__ void __launch_bounds__(256, 1)
rnn_persist(const float* __restrict__ x, const float* __restrict__ Wxh,
            const float* __restrict__ Whh, const float* __restrict__ bh,
            float* __restrict__ out, u32* __restrict__ hglob)
{
    __shared__ __align__(16) f16 xlds[2][4 * ROWP];
    __shared__ __align__(16) f16 hlds[4 * ROWP];

    const int tid  = threadIdx.x;
    const int lane = tid & 63;
    const int wv   = tid >> 6;
    const int g    = (lane >> 4) & 3;   // k-group within wave
    const int l15  = lane & 15;

    const int bidx    = blockIdx.x;
    const int cluster = ((bidx & 7) << 1) | ((bidx >> 3) & 1);  // perf-only XCD grouping
    const int member  = bidx >> 4;
    const int bbase   = cluster * 4;                 // 4 batches per cluster
    const int n       = member * 64 + wv * 16 + l15; // feature this lane owns

    // ---- weight fragments resident in VGPRs (fp16) ----
    f16x8 bx[32], bw[32];
#pragma unroll
    for (int kt = 0; kt < 32; ++kt) {
        const float* px = Wxh + (size_t)n * NH + kt * 32 + g * 8;
        const float* pw = Whh + (size_t)n * NH + kt * 32 + g * 8;
        float4 a0 = ((const float4*)px)[0], a1 = ((const float4*)px)[1];
        float4 c0 = ((const float4*)pw)[0], c1 = ((const float4*)pw)[1];
        bx[kt] = cvt8(a0, a1);
        bw[kt] = cvt8(c0, c1);
    }
    const float bias = bh[n];

    // ---- staging geometry ----
    const int sb = wv;                 // wave owns one batch row of the cluster's 4
    const float* xsrc0 = x + (size_t)(bbase + sb) * NH + lane * 16;
    f16* xd0  = &xlds[0][sb * ROWP + lane * 16];
    f16* xd1  = &xlds[1][sb * ROWP + lane * 16];
    f16* hdst = &hlds[sb * ROWP + lane * 16];

    const f16* xa0 = &xlds[0][(l15 & 3) * ROWP + g * 8];
    const f16* xa1 = &xlds[1][(l15 & 3) * ROWP + g * 8];
    const f16* ha  = &hlds[(l15 & 3) * ROWP + g * 8];

    float4 xr0, xr1, xr2, xr3;         // x prefetch regs (x_{t+2} on entry to iter t)
    u32 w[16];                         // tagged h words for my 16 feats of row sb
    f32x4 acc[8];
    float hvv[4];

    auto load_x = [&](int t) {
        const float4* p = (const float4*)(xsrc0 + (size_t)t * (NB * NH));
        xr0 = p[0]; xr1 = p[1]; xr2 = p[2]; xr3 = p[3];
    };
    auto write_x = [&](int par) {
        f16* d = par ? xd1 : xd0;
        *(f16x8*)d       = cvt8(xr0, xr1);
        *(f16x8*)(d + 8) = cvt8(xr2, xr3);
    };
    auto zero_acc = [&]() {
#pragma unroll
        for (int i = 0; i < 8; ++i) acc[i] = f32x4{0.f, 0.f, 0.f, 0.f};
    };
    auto mfma_x = [&](const f16* xa) {
#pragma unroll
        for (int kt = 0; kt < 32; ++kt)
            acc[kt & 7] = __builtin_amdgcn_mfma_f32_16x16x32_f16(
                *(const f16x8*)(xa + kt * 32), bx[kt], acc[kt & 7], 0, 0, 0);
    };
    auto mfma_h = [&]() {
#pragma unroll
        for (int kt = 0; kt < 32; ++kt)
            acc[(kt + 4) & 7] = __builtin_amdgcn_mfma_f32_16x16x32_f16(
                *(const f16x8*)(ha + kt * 32), bw[kt], acc[(kt + 4) & 7], 0, 0, 0);
    };
    // poll my row's tagged words until all 16 tags == t; words are the data.
    auto poll_h = [&](int t) {
        const u32* s = hglob + ((size_t)((t & 1) * NB + bbase + sb)) * NH + lane * 16;
        int guard = 1 << 16;  // hang-safety: wrong-but-terminating
        for (;;) {
            bool ok = true;
#pragma unroll
            for (int i = 0; i < 16; ++i) {
                w[i] = __hip_atomic_load(s + i, __ATOMIC_RELAXED, __HIP_MEMORY_SCOPE_AGENT);
                ok &= ((w[i] >> 16) == (u32)t);
            }
            if (__all(ok)) break;
            if (--guard == 0) break;
        }
    };
    auto stage_h_write = [&]() {  // strip tags, pack fp16, stage to LDS
        f16x8 lo, hi;
#pragma unroll
        for (int i = 0; i < 8; ++i) {
            lo[i] = __builtin_bit_cast(f16, (u16)(w[i] & 0xffffu));
            hi[i] = __builtin_bit_cast(f16, (u16)(w[8 + i] & 0xffffu));
        }
        *(f16x8*)hdst       = lo;
        *(f16x8*)(hdst + 8) = hi;
    };
    // reduce acc, tanh, fire tagged h_{t+1} (serial-chain tail; no vmcnt wait)
    auto compute_h = [&](int t) {
        f32x4 s = ((acc[0] + acc[1]) + (acc[2] + acc[3])) +
                  ((acc[4] + acc[5]) + (acc[6] + acc[7]));
        if (lane < 16) {
            const int par = (t + 1) & 1;
#pragma unroll
            for (int r = 0; r < 4; ++r) {
                float hv = fast_tanh(s[r] + bias);
                hvv[r] = hv;
                if (t < T_STEPS - 1) {
                    u32 word = ((u32)(t + 1) << 16) |
                               (u32)__builtin_bit_cast(u16, (f16)hv);
                    __hip_atomic_store(
                        hglob + ((size_t)par * NB + bbase + r) * NH + n, word,
                        __ATOMIC_RELAXED, __HIP_MEMORY_SCOPE_AGENT);
                }
            }
        }
    };
    auto out_stores = [&](int t) {  // off-chain fp32 output
        if (lane < 16) {
#pragma unroll
            for (int r = 0; r < 4; ++r) {
                const int b = bbase + r;
                __builtin_nontemporal_store(hvv[r], out + ((size_t)t * NB + b) * NH + n);
                if (t == T_STEPS - 1)
                    __builtin_nontemporal_store(
                        hvv[r], out + (size_t)T_STEPS * NB * NH + (size_t)b * NH + n);
            }
        }
    };

    // ---- prologue: fill xlds[0], xlds[1]; acc = x-part of step 0 ----
    load_x(0); write_x(0);
    load_x(1);
    lds_barrier();                 // xlds[0] ready (all waves)
    write_x(1);                    // xlds[1] (ready via iter-0 phase-A barrier)
    load_x(2);                     // xr = x_2  (invariant entering iter 0)
    zero_acc();
    mfma_x(xa0);                   // acc = x-part(0)

    // ---- main loop ----
    for (int t = 0; t < T_STEPS; ++t) {
        if (t > 0) {               // serial head: h_t arrives (poll == data load)
            poll_h(t);
            stage_h_write();
        }
        lds_barrier();             // hlds ready; xlds[(t+1)&1] ready
        if (t > 0) mfma_h();
        compute_h(t);              // serial tail: fire tagged h_{t+1}
        out_stores(t);
        if (t < T_STEPS - 1) {     // off-chain x work for the next step
            zero_acc();
            mfma_x(((t + 1) & 1) ? xa1 : xa0);
            if (t <= T_STEPS - 3) write_x(t & 1);  // x_{t+2} -> xlds[(t+2)&1]
            if (t <= T_STEPS - 4) load_x(t + 3);
            lds_barrier();         // xlds writes visible; hlds WAR guard
        }
    }
}

extern "C" void kernel_launch(void* const* d_in, const int* in_sizes, int n_in,
                              void* d_out, int out_size, void* d_ws, size_t ws_size,
                              hipStream_t stream) {
    const float* x   = (const float*)d_in[0];
    const float* Wxh = (const float*)d_in[1];
    const float* Whh = (const float*)d_in[2];
    const float* bh  = (const float*)d_in[3];
    float* out       = (float*)d_out;
    u32* hglob       = (u32*)d_ws;   // 512 KB tagged h, poison-safe (0xAAAA tag)
    rnn_persist<<<dim3(256), dim3(256), 0, stream>>>(x, Wxh, Whh, bh, out, hglob);
}

// Round 5
// 2106.012 us; speedup vs baseline: 1.2801x; 1.2801x over previous
//
#include <hip/hip_runtime.h>

// SlowRNN: out[t] = h_{t+1} = tanh(x_t @ Wxh^T + bh + h_t @ Whh^T), h_0 = 0
// T=512, B=64, IN=H=1024.  fp32 in / fp32 out, threshold 2e-2 -> fp16 MFMA compute.
//
// v4: v3's tagged single-round-trip h exchange, with the poll COALESCED.
//  - h word = (tag<<16 | fp16bits), relaxed agent-scope (sc1). Poll IS the load.
//  - Lane L owns features {j*64+L}: each poll load instruction covers 64
//    consecutive dwords = 4 lines (was 64 lines/instr in v3 -> 16x fewer MALL
//    transactions per round; re-polling is cheap).
//  - First poll round for t+1 issued right after firing h_{t+1}; x-side work
//    (out stores, mfma_x, x staging) runs while the loads fly.
//  - ONE lds_barrier per step: passing the tag check proves all producers fired
//    h_{t+1}, which data-depends on their mfma_h(t) having consumed hlds ->
//    stage overwrite is WAR-safe without a second barrier.
//  - Tags 1..511 never collide with 0xAAAA ws-poison; parity double-buffer is
//    ABA-free (slot alternates t / t+2 tags). No ws memset needed.
// ws: hglob u32[2][64][1024] @0 (512KB).

typedef _Float16 f16;
typedef _Float16 f16x8 __attribute__((ext_vector_type(8)));
typedef float f32x4 __attribute__((ext_vector_type(4)));
typedef unsigned int u32;
typedef unsigned short u16;

#define T_STEPS 512
#define NB 64
#define NH 1024
#define ROWP 1040  // padded LDS row (f16 elems), 2080B stride

__device__ __forceinline__ f16x8 cvt8(const float4 a, const float4 b) {
    f16x8 v;
    v[0] = (f16)a.x; v[1] = (f16)a.y; v[2] = (f16)a.z; v[3] = (f16)a.w;
    v[4] = (f16)b.x; v[5] = (f16)b.y; v[6] = (f16)b.z; v[7] = (f16)b.w;
    return v;
}

__device__ __forceinline__ float fast_tanh(float x) {
    float e = __expf(2.0f * x);
    return 1.0f - 2.0f / (e + 1.0f);
}

__device__ __forceinline__ void lds_barrier() {
    // LDS-only drain + barrier: vmcnt traffic (x prefetch, out/h stores, polls)
    // stays in flight across the barrier.
    asm volatile("s_waitcnt lgkmcnt(0)\ns_barrier" ::: "memory");
}

extern "C" __global__ void __launch_bounds__(256, 1)
rnn_persist(const float* __restrict__ x, const float* __restrict__ Wxh,
            const float* __restrict__ Whh, const float* __restrict__ bh,
            float* __restrict__ out, u32* __restrict__ hglob)
{
    __shared__ __align__(16) f16 xlds[2][4 * ROWP];
    __shared__ __align__(16) f16 hlds[4 * ROWP];

    const int tid  = threadIdx.x;
    const int lane = tid & 63;
    const int wv   = tid >> 6;
    const int g    = (lane >> 4) & 3;   // k-group within wave
    const int l15  = lane & 15;

    const int bidx    = blockIdx.x;
    const int cluster = ((bidx & 7) << 1) | ((bidx >> 3) & 1);  // perf-only XCD grouping
    const int member  = bidx >> 4;
    const int bbase   = cluster * 4;                 // 4 batches per cluster
    const int n       = member * 64 + wv * 16 + l15; // feature this lane owns

    // ---- weight fragments resident in VGPRs (fp16) ----
    f16x8 bx[32], bw[32];
#pragma unroll
    for (int kt = 0; kt < 32; ++kt) {
        const float* px = Wxh + (size_t)n * NH + kt * 32 + g * 8;
        const float* pw = Whh + (size_t)n * NH + kt * 32 + g * 8;
        float4 a0 = ((const float4*)px)[0], a1 = ((const float4*)px)[1];
        float4 c0 = ((const float4*)pw)[0], c1 = ((const float4*)pw)[1];
        bx[kt] = cvt8(a0, a1);
        bw[kt] = cvt8(c0, c1);
    }
    const float bias = bh[n];

    // ---- staging geometry ----
    const int sb = wv;                 // wave owns one batch row of the cluster's 4
    const float* xsrc0 = x + (size_t)(bbase + sb) * NH + lane * 16;
    f16* xd0  = &xlds[0][sb * ROWP + lane * 16];
    f16* xd1  = &xlds[1][sb * ROWP + lane * 16];
    f16* hrow = &hlds[sb * ROWP];      // h stage dest (lane L -> elems j*64+L)

    const f16* xa0 = &xlds[0][(l15 & 3) * ROWP + g * 8];
    const f16* xa1 = &xlds[1][(l15 & 3) * ROWP + g * 8];
    const f16* ha  = &hlds[(l15 & 3) * ROWP + g * 8];

    // coalesced poll bases: lane L reads dwords {j*64+L} of its row, per parity
    const u32* hp0 = hglob + (size_t)(bbase + sb) * NH + lane;
    const u32* hp1 = hglob + (size_t)(NB + bbase + sb) * NH + lane;

    float4 xr0, xr1, xr2, xr3;         // x prefetch regs (x_{t+2} entering iter t)
    u32 w[16];                         // tagged h words (feature j*64+lane)
    f32x4 acc[8];
    float hvv[4];

    auto load_x = [&](int t) {
        const float4* p = (const float4*)(xsrc0 + (size_t)t * (NB * NH));
        xr0 = p[0]; xr1 = p[1]; xr2 = p[2]; xr3 = p[3];
    };
    auto write_x = [&](int par) {
        f16* d = par ? xd1 : xd0;
        *(f16x8*)d       = cvt8(xr0, xr1);
        *(f16x8*)(d + 8) = cvt8(xr2, xr3);
    };
    auto zero_acc = [&]() {
#pragma unroll
        for (int i = 0; i < 8; ++i) acc[i] = f32x4{0.f, 0.f, 0.f, 0.f};
    };
    auto mfma_x = [&](const f16* xa) {
#pragma unroll
        for (int kt = 0; kt < 32; ++kt)
            acc[kt & 7] = __builtin_amdgcn_mfma_f32_16x16x32_f16(
                *(const f16x8*)(xa + kt * 32), bx[kt], acc[kt & 7], 0, 0, 0);
    };
    auto mfma_h = [&]() {
#pragma unroll
        for (int kt = 0; kt < 32; ++kt)
            acc[(kt + 4) & 7] = __builtin_amdgcn_mfma_f32_16x16x32_f16(
                *(const f16x8*)(ha + kt * 32), bw[kt], acc[(kt + 4) & 7], 0, 0, 0);
    };
    auto issue_poll = [&](int t) {  // one coalesced round of tagged h_t loads
        const u32* s = (t & 1) ? hp1 : hp0;
#pragma unroll
        for (int j = 0; j < 16; ++j)
            w[j] = __hip_atomic_load(s + (size_t)j * 64, __ATOMIC_RELAXED,
                                     __HIP_MEMORY_SCOPE_AGENT);
    };
    auto tags_ok = [&](int t) {
        bool ok = true;
#pragma unroll
        for (int j = 0; j < 16; ++j) ok &= ((w[j] >> 16) == (u32)t);
        return __all((int)ok) != 0;
    };
    auto stage_h = [&]() {  // strip tags -> f16 -> LDS (2B lane stride: conflict-free)
#pragma unroll
        for (int j = 0; j < 16; ++j)
            hrow[j * 64 + lane] = __builtin_bit_cast(f16, (u16)(w[j] & 0xffffu));
    };
    // reduce acc, tanh, fire tagged h_{t+1} (fire-and-forget; no vmcnt wait)
    auto compute_h = [&](int t) {
        f32x4 s = ((acc[0] + acc[1]) + (acc[2] + acc[3])) +
                  ((acc[4] + acc[5]) + (acc[6] + acc[7]));
        if (lane < 16) {
            const int par = (t + 1) & 1;
#pragma unroll
            for (int r = 0; r < 4; ++r) {
                float hv = fast_tanh(s[r] + bias);
                hvv[r] = hv;
                if (t < T_STEPS - 1) {
                    u32 word = ((u32)(t + 1) << 16) |
                               (u32)__builtin_bit_cast(u16, (f16)hv);
                    __hip_atomic_store(
                        hglob + ((size_t)par * NB + bbase + r) * NH + n, word,
                        __ATOMIC_RELAXED, __HIP_MEMORY_SCOPE_AGENT);
                }
            }
        }
    };
    auto out_stores = [&](int t) {  // off-chain fp32 output
        if (lane < 16) {
#pragma unroll
            for (int r = 0; r < 4; ++r) {
                const int b = bbase + r;
                __builtin_nontemporal_store(hvv[r], out + ((size_t)t * NB + b) * NH + n);
                if (t == T_STEPS - 1)
                    __builtin_nontemporal_store(
                        hvv[r], out + (size_t)T_STEPS * NB * NH + (size_t)b * NH + n);
            }
        }
    };

    // ---- prologue ----
    load_x(0); write_x(0);         // xlds[0] = x_0
    load_x(1);
    lds_barrier();                 // xlds[0] visible
    zero_acc();
    mfma_x(xa0);                   // acc = x-part(0)
    write_x(1);                    // xlds[1] = x_1 (visible via barrier in iter 0)
    load_x(2);                     // regs = x_2 (invariant entering iter 0)

    // ---- main loop: one barrier per step ----
    for (int t = 0; t < T_STEPS; ++t) {
        if (t > 0) {
            if (!tags_ok(t)) {                     // fast path: round issued last iter
                int guard = 1 << 15;               // hang-safety: terminating on deadlock
                do { issue_poll(t); } while (!tags_ok(t) && --guard);
            }
            stage_h();
        }
        lds_barrier();             // hlds(t) ready; xlds[(t+1)&1] ready; WAR via tags
        if (t > 0) mfma_h();
        compute_h(t);              // serial tail: fire tagged h_{t+1}
        if (t < T_STEPS - 1) issue_poll(t + 1);    // first round in flight
        out_stores(t);
        if (t < T_STEPS - 1) {     // off-chain x work while poll loads fly
            zero_acc();
            mfma_x(((t + 1) & 1) ? xa1 : xa0);     // x-part(t+1)
            if (t <= T_STEPS - 3) write_x(t & 1);  // x_{t+2} -> xlds[(t+2)&1]
            if (t <= T_STEPS - 4) load_x(t + 3);
        }
    }
}

extern "C" void kernel_launch(void* const* d_in, const int* in_sizes, int n_in,
                              void* d_out, int out_size, void* d_ws, size_t ws_size,
                              hipStream_t stream) {
    const float* x   = (const float*)d_in[0];
    const float* Wxh = (const float*)d_in[1];
    const float* Whh = (const float*)d_in[2];
    const float* bh  = (const float*)d_in[3];
    float* out       = (float*)d_out;
    u32* hglob       = (u32*)d_ws;   // 512 KB tagged h; poison-safe (0xAAAA tag)
    rnn_persist<<<dim3(256), dim3(256), 0, stream>>>(x, Wxh, Whh, bh, out, hglob);
}